// Round 6
// baseline (221.422 us; speedup 1.0000x reference)
//
#include <hip/hip_runtime.h>
#include <hip/hip_bf16.h>

#define NPER 68
#define ROWP 80
#define EPER 544
#define FH   128
#define NC   8
#define AJW  104   // adjb/sT row stride (elem): 208B=52dw==20 mod 32 -> conflict-free
#define HTW  88    // hT row stride (elem): 176B=44dw==12 mod 32 -> conflict-free

typedef short short8 __attribute__((ext_vector_type(8)));
typedef float f32x4 __attribute__((ext_vector_type(4)));
typedef unsigned short ushort4v __attribute__((ext_vector_type(4)));

__device__ __forceinline__ unsigned short f2bf(float f) {
    unsigned int u = __float_as_uint(f);
    return (unsigned short)((u + 0x7FFFu + ((u >> 16) & 1u)) >> 16);
}
__device__ __forceinline__ unsigned short f2bf_c(float f) {   // compiler cvt path (RNE)
    __hip_bfloat16 b = __float2bfloat16(f);
    return __builtin_bit_cast(unsigned short, b);
}
__device__ __forceinline__ float bf2f(unsigned short h) {
    return __uint_as_float(((unsigned int)h) << 16);
}
// bcat swizzle: row stride 512B; XOR 16B-unit bits 4..6 with (row^(row>>3))&7.
__device__ __forceinline__ unsigned int swzB(unsigned int row, unsigned int bc) {
    return row * 512u + (bc ^ (((row ^ (row >> 3)) & 7u) << 4));
}

// Pack [Wrel;Wroot] (256x128 f32) into MFMA-B-fragment-ordered bf16 (layers 2,3):
// ws[(((L*8+t)*8+n)*64+l)*8+j] = Wcat[t*32+(l>>4)*8+j][n*16+(l&15)]
__global__ void pack_w(const float* __restrict__ Wrel2, const float* __restrict__ Wroot2,
                       const float* __restrict__ Wrel3, const float* __restrict__ Wroot3,
                       unsigned short* __restrict__ ws) {
    int o = blockIdx.x * 256 + threadIdx.x;      // < 65536
    int j = o & 7, l = (o >> 3) & 63, n = (o >> 9) & 7, t = (o >> 12) & 7, L = o >> 15;
    int k = t * 32 + ((l >> 4) << 3) + j;
    int f = n * 16 + (l & 15);
    const float* Wl = L ? Wrel3 : Wrel2;
    const float* Wr = L ? Wroot3 : Wroot2;
    float v = (k < FH) ? Wl[k * FH + f] : Wr[(k - FH) * FH + f];
    ws[o] = f2bf(v);
}

// One block per graph, 256 threads = 4 waves. LDS ~85KB -> 2 blocks/CU.
__launch_bounds__(256, 2)
__global__ void gnn_kernel(const float* __restrict__ x,
                           const int*   __restrict__ ei,
                           const float* __restrict__ s,
                           const float* __restrict__ Wroot1, const float* __restrict__ Wrel1,
                           const float* __restrict__ b1,
                           const float* __restrict__ b2, const float* __restrict__ b3,
                           const unsigned short* __restrict__ wpack,
                           const float* __restrict__ fcw, const float* __restrict__ fcb,
                           float* __restrict__ out, int nE)
{
    // bcat[row][k]: k 0..127 agg part, 128..255 h part (bf16, swizzled rows)
    __shared__ __align__(16) unsigned short bcat[ROWP * 256];   // 40960 B
    __shared__ __align__(16) unsigned short hT[FH * HTW];       // 22528 B  h^T[f][node]
    __shared__ __align__(16) unsigned short adjb[ROWP * AJW];   // 16640 B  (xp/red overlay later)
    __shared__ __align__(16) unsigned short sT[16 * AJW];       // 3328 B   softmax(s)^T
    __shared__ float xl[NPER][2];                               // 544 B

    const int g = blockIdx.x, tid = threadIdx.x, lane = tid & 63, wid = tid >> 6;
    const int gnode = g * NPER, gedge = g * EPER;
    const int* srcp = ei;
    const int* dstp = ei + nE;
    unsigned int* adj32 = (unsigned int*)adjb;
    unsigned int* h32   = (unsigned int*)bcat;
    unsigned int* ht32  = (unsigned int*)hT;

    // ---- zero init ----
    for (int i = tid; i < (ROWP * AJW) / 2; i += 256) adj32[i] = 0u;
    for (int i = tid; i < (16 * AJW) / 2; i += 256) ((unsigned int*)sT)[i] = 0u;
    for (int i = tid; i < 12 * 128; i += 256) h32[NPER * 128 + i] = 0u;           // bcat rows 68..79
    for (int i = tid; i < NPER * 32; i += 256) h32[(i >> 5) * 128 + (i & 31)] = 0u; // bcat rows<68 agg cols 0..63
    for (int i = tid; i < 128 * 10; i += 256) ht32[(i / 10) * (HTW / 2) + 34 + (i % 10)] = 0u; // hT cols 68..87
    for (int i = tid; i < NPER * 2; i += 256) ((float*)xl)[i] = x[gnode * 2 + i];
    __syncthreads();

    // ---- edges -> adjacency counts (u16 halves of u32, atomic) ----
    for (int e = tid; e < EPER; e += 256) {
        int s_ = srcp[gedge + e] - gnode;
        int d_ = dstp[gedge + e] - gnode;
        int idx = d_ * AJW + s_;
        atomicAdd(&adj32[idx >> 1], (idx & 1) ? 0x10000u : 1u);
    }
    __syncthreads();
    // in-place convert u16 counts -> bf16
    for (int i = tid; i < (ROWP * AJW) / 2; i += 256) {
        unsigned int u = adj32[i];
        if (u) {
            adj32[i] = (unsigned int)f2bf((float)(u & 0xffffu))
                     | ((unsigned int)f2bf((float)(u >> 16)) << 16);
        }
    }
    __syncthreads();

    // ---- layer-1 A prep (aggx via Adj row-dot) + softmax(s)^T ----
    if (tid < 136) {
        int i = tid >> 1, ft = tid & 1;
        float a = 0.f;
        for (int j = 0; j < NPER; ++j) a += bf2f(adjb[i * AJW + j]) * xl[j][ft];
        *(unsigned short*)((char*)bcat + swzB(i, ft * 2))     = f2bf(a);
        *(unsigned short*)((char*)bcat + swzB(i, 4 + ft * 2)) = f2bf(xl[i][ft]);
    } else if (tid < 204) {
        int i = tid - 136;
        float v[NC]; float m = -1e30f;
        #pragma unroll
        for (int c = 0; c < NC; ++c) { v[c] = s[(gnode + i) * NC + c]; m = fmaxf(m, v[c]); }
        float sum = 0.f;
        #pragma unroll
        for (int c = 0; c < NC; ++c) { v[c] = __expf(v[c] - m); sum += v[c]; }
        float inv = 1.f / sum;
        #pragma unroll
        for (int c = 0; c < NC; ++c) sT[c * AJW + i] = f2bf(v[c] * inv);
    }
    __syncthreads();

    const int arow = lane & 15, aq = lane >> 4, akB = aq * 16, akE = aq * 8;

    // epilogue: acc + bias -> relu -> bcat h-half (scalar) AND hT (b64 per 4 rows)
    auto epilogue_h = [&](f32x4 (&acc)[5][2], const float* __restrict__ bv) {
        #pragma unroll
        for (int c2 = 0; c2 < 2; ++c2) {
            int f = (wid * 2 + c2) * 16 + arow;
            float bias = bv[f];
            #pragma unroll
            for (int m = 0; m < 5; ++m) {
                int rbase = m * 16 + aq * 4;
                if (rbase < NPER) {                 // rbase multiple of 4; rbase+3 <= 67
                    ushort4v w;
                    #pragma unroll
                    for (int i2 = 0; i2 < 4; ++i2) {
                        float v = acc[m][c2][i2] + bias;
                        v = v > 0.f ? v : 0.f;
                        unsigned short us = f2bf_c(v);
                        w[i2] = us;
                        *(unsigned short*)((char*)bcat + swzB(rbase + i2, (FH + f) * 2)) = us;
                    }
                    *(ushort4v*)(hT + f * HTW + rbase) = w;
                }
            }
        }
    };

    // ---- layer 1: h = relu([aggx|x] @ Wcat1 + b1), K=32 MFMA ----
    {
        f32x4 acc[5][2];
        #pragma unroll
        for (int m = 0; m < 5; ++m) { acc[m][0] = (f32x4)0.f; acc[m][1] = (f32x4)0.f; }
        short8 bf[2];
        #pragma unroll
        for (int c2 = 0; c2 < 2; ++c2) {
            int f = (wid * 2 + c2) * 16 + arow;
            #pragma unroll
            for (int j = 0; j < 8; ++j) {
                float wv = 0.f;
                if (aq == 0) {              // k = j, only k<4 nonzero
                    if (j < 2) wv = Wrel1[j * FH + f];
                    else if (j < 4) wv = Wroot1[(j - 2) * FH + f];
                }
                bf[c2][j] = (short)f2bf(wv);
            }
        }
        #pragma unroll
        for (int m = 0; m < 5; ++m) {
            short8 a = *(const short8*)((char*)bcat + swzB(m * 16 + arow, akB));
            acc[m][0] = __builtin_amdgcn_mfma_f32_16x16x32_bf16(a, bf[0], acc[m][0], 0, 0, 0);
            acc[m][1] = __builtin_amdgcn_mfma_f32_16x16x32_bf16(a, bf[1], acc[m][1], 0, 0, 0);
        }
        epilogue_h(acc, b1);   // L1 A-reads hit agg-half only, no overlap with h-half writes
    }
    __syncthreads();

    // ---- layers 2,3: agg = Adj@h (B from hT), then h' = relu([agg|h]@Wcat+b) ----
    #pragma unroll 1
    for (int L = 0; L < 2; ++L) {
        // agg GEMM: A=adjb rows, B = h[src][f] = hT[f][src..src+8] contiguous
        f32x4 acc[5][2];
        #pragma unroll
        for (int m = 0; m < 5; ++m) { acc[m][0] = (f32x4)0.f; acc[m][1] = (f32x4)0.f; }
        #pragma unroll
        for (int kt = 0; kt < 3; ++kt) {
            int cb = kt * 32 + akE; if (cb >= HTW) cb = 0;   // OOB k: Adj cols zero kill it
            short8 bg[2];
            #pragma unroll
            for (int c2 = 0; c2 < 2; ++c2) {
                int f = (wid * 2 + c2) * 16 + arow;
                bg[c2] = *(const short8*)(hT + f * HTW + cb);
            }
            #pragma unroll
            for (int m = 0; m < 5; ++m) {
                short8 a = *(const short8*)(adjb + (m * 16 + arow) * AJW + kt * 32 + akE);
                acc[m][0] = __builtin_amdgcn_mfma_f32_16x16x32_bf16(a, bg[0], acc[m][0], 0, 0, 0);
                acc[m][1] = __builtin_amdgcn_mfma_f32_16x16x32_bf16(a, bg[1], acc[m][1], 0, 0, 0);
            }
        }
        // agg epilogue -> bcat agg-half (no bias/relu), rows < 68
        #pragma unroll
        for (int c2 = 0; c2 < 2; ++c2) {
            int f = (wid * 2 + c2) * 16 + arow;
            #pragma unroll
            for (int m = 0; m < 5; ++m) {
                int rbase = m * 16 + aq * 4;
                if (rbase < NPER) {
                    #pragma unroll
                    for (int i2 = 0; i2 < 4; ++i2)
                        *(unsigned short*)((char*)bcat + swzB(rbase + i2, f * 2)) = f2bf_c(acc[m][c2][i2]);
                }
            }
        }
        __syncthreads();

        // main GEMM: [agg|h] @ Wcat, K=256; A=bcat rows, B=wpack (global, L2)
        f32x4 acc2[5][2];
        #pragma unroll
        for (int m = 0; m < 5; ++m) { acc2[m][0] = (f32x4)0.f; acc2[m][1] = (f32x4)0.f; }
        const unsigned short* wsL = wpack + (L << 15);
        for (int t = 0; t < 8; ++t) {
            short8 bf0 = *(const short8*)(wsL + (((t * 8 + wid * 2 + 0) * 64 + lane) << 3));
            short8 bf1 = *(const short8*)(wsL + (((t * 8 + wid * 2 + 1) * 64 + lane) << 3));
            #pragma unroll
            for (int m = 0; m < 5; ++m) {
                short8 a = *(const short8*)((char*)bcat + swzB(m * 16 + arow, t * 64 + akB));
                acc2[m][0] = __builtin_amdgcn_mfma_f32_16x16x32_bf16(a, bf0, acc2[m][0], 0, 0, 0);
                acc2[m][1] = __builtin_amdgcn_mfma_f32_16x16x32_bf16(a, bf1, acc2[m][1], 0, 0, 0);
            }
        }
        __syncthreads();                 // all A reads done before h/hT overwrite
        epilogue_h(acc2, L ? b3 : b2);
        __syncthreads();
    }

    // ---- diff-pool: xp = sT @ h (B from hT), M=16 rows 8..15 zero ----
    float* xpf = (float*)adjb;           // overlay: adjb dead after L3 agg GEMM
    {
        f32x4 accp[2]; accp[0] = (f32x4)0.f; accp[1] = (f32x4)0.f;
        #pragma unroll
        for (int kt = 0; kt < 3; ++kt) {
            int cb = kt * 32 + akE; if (cb >= HTW) cb = 0;   // OOB k: sT cols zero
            short8 bg[2];
            #pragma unroll
            for (int c2 = 0; c2 < 2; ++c2) {
                int f = (wid * 2 + c2) * 16 + arow;
                bg[c2] = *(const short8*)(hT + f * HTW + cb);
            }
            short8 a = *(const short8*)(sT + arow * AJW + kt * 32 + akE);
            accp[0] = __builtin_amdgcn_mfma_f32_16x16x32_bf16(a, bg[0], accp[0], 0, 0, 0);
            accp[1] = __builtin_amdgcn_mfma_f32_16x16x32_bf16(a, bg[1], accp[1], 0, 0, 0);
        }
        #pragma unroll
        for (int c2 = 0; c2 < 2; ++c2) {
            int f = (wid * 2 + c2) * 16 + arow;
            if (aq < 2) {
                #pragma unroll
                for (int i2 = 0; i2 < 4; ++i2) xpf[(aq * 4 + i2) * FH + f] = accp[c2][i2];
            }
        }
    }
    __syncthreads();

    // ---- maxpool (1,8) + FC ----
    float* red = xpf + NC * FH;
    float partial = 0.f;
    if (tid < 128) {
        int c = tid >> 4, q = tid & 15;
        float m = xpf[c * FH + q * 8];
        #pragma unroll
        for (int j = 1; j < 8; ++j) m = fmaxf(m, xpf[c * FH + q * 8 + j]);
        partial = m * fcw[tid];
    }
    if (tid < 128) red[tid] = partial;
    __syncthreads();
    if (tid < 64) {
        float v = red[tid] + red[tid + 64];
        #pragma unroll
        for (int off = 32; off > 0; off >>= 1) v += __shfl_down(v, off, 64);
        if (tid == 0) out[g] = v + fcb[0];
    }
}

extern "C" void kernel_launch(void* const* d_in, const int* in_sizes, int n_in,
                              void* d_out, int out_size, void* d_ws, size_t ws_size,
                              hipStream_t stream) {
    const float* x      = (const float*)d_in[0];
    const int*   ei     = (const int*)d_in[1];
    // d_in[2] = adj: dead code in the reference
    const float* s      = (const float*)d_in[3];
    const float* Wroot1 = (const float*)d_in[4];
    const float* Wrel1  = (const float*)d_in[5];
    const float* b1     = (const float*)d_in[6];
    const float* Wroot2 = (const float*)d_in[7];
    const float* Wrel2  = (const float*)d_in[8];
    const float* b2     = (const float*)d_in[9];
    const float* Wroot3 = (const float*)d_in[10];
    const float* Wrel3  = (const float*)d_in[11];
    const float* b3     = (const float*)d_in[12];
    const float* fcw    = (const float*)d_in[13];
    const float* fcb    = (const float*)d_in[14];
    float* out = (float*)d_out;
    unsigned short* wpack = (unsigned short*)d_ws;   // 65536 bf16 = 128 KB

    const int nE = in_sizes[1] / 2;
    const int B  = in_sizes[3] / (NPER * NC);

    pack_w<<<256, 256, 0, stream>>>(Wrel2, Wroot2, Wrel3, Wroot3, wpack);
    gnn_kernel<<<B, 256, 0, stream>>>(x, ei, s,
                                      Wroot1, Wrel1, b1,
                                      b2, b3, wpack,
                                      fcw, fcb, out, nE);
}

// Round 8
// 180.427 us; speedup vs baseline: 1.2272x; 1.2272x over previous
//
#include <hip/hip_runtime.h>
#include <hip/hip_bf16.h>

#define NPER 68
#define EPER 544
#define FH   128
#define NC   8
#define AJW  104   // adjb/sT row stride (elem): 52dw == 20 mod 32 -> 2-way per quarter-wave (free)
#define HTW  88    // hT row stride (elem): 44dw == 12 mod 32 -> 2-way per quarter-wave (free)

// ---- flat LDS layout (order fixed; spill reads must stay < SMEM_TOTAL) ----
// bcat [68][256] bf16 swizzled @ 0      (34816 B; A-reads spill to 40960 max -> discarded D rows)
// hT   [128][88] bf16          @ 34816  (22528 B)
// adjb [68][104] bf16          @ 57344  (14144 B; row-spill reads -> discarded D rows)
// sT   [16][104] bf16          @ 71488  (3328 B; rows 8..15 uninit -> D rows discarded, never read)
// xl   [68][2]   f32           @ 74816  (544 B)
// xpf  [8][128]+red overlay    @ 57344  (4608 B, after adjb dead)
#define SMEM_TOTAL 75360
#define OFF_HT   34816
#define OFF_ADJ  57344
#define OFF_ST   71488
#define OFF_XL   74816

typedef short short8 __attribute__((ext_vector_type(8)));
typedef float f32x4 __attribute__((ext_vector_type(4)));
typedef unsigned short ushort4v __attribute__((ext_vector_type(4)));

__device__ __forceinline__ unsigned short f2bf(float f) {
    unsigned int u = __float_as_uint(f);
    return (unsigned short)((u + 0x7FFFu + ((u >> 16) & 1u)) >> 16);
}
__device__ __forceinline__ unsigned short f2bf_c(float f) {
    __hip_bfloat16 b = __float2bfloat16(f);
    return __builtin_bit_cast(unsigned short, b);
}
__device__ __forceinline__ float bf2f(unsigned short h) {
    return __uint_as_float(((unsigned int)h) << 16);
}
// bcat swizzle: row stride 512B; XOR 16B-unit bits 4..6 with (row^(row>>3))&7.
__device__ __forceinline__ unsigned int swzB(unsigned int row, unsigned int bc) {
    return row * 512u + (bc ^ (((row ^ (row >> 3)) & 7u) << 4));
}

// Pack [Wrel;Wroot] (256x128 f32) into MFMA-B-fragment-ordered bf16 (layers 2,3):
// ws[(((L*8+t)*8+n)*64+l)*8+j] = Wcat[t*32+(l>>4)*8+j][n*16+(l&15)]
__global__ void pack_w(const float* __restrict__ Wrel2, const float* __restrict__ Wroot2,
                       const float* __restrict__ Wrel3, const float* __restrict__ Wroot3,
                       unsigned short* __restrict__ ws) {
    int o = blockIdx.x * 256 + threadIdx.x;      // < 65536
    int j = o & 7, l = (o >> 3) & 63, n = (o >> 9) & 7, t = (o >> 12) & 7, L = o >> 15;
    int k = t * 32 + ((l >> 4) << 3) + j;
    int f = n * 16 + (l & 15);
    const float* Wl = L ? Wrel3 : Wrel2;
    const float* Wr = L ? Wroot3 : Wroot2;
    float v = (k < FH) ? Wl[k * FH + f] : Wr[(k - FH) * FH + f];
    ws[o] = f2bf(v);
}

// One block per graph, 256 threads = 4 waves. LDS 75360 B -> 2 blocks/CU.
__launch_bounds__(256, 2)
__global__ void gnn_kernel(const float* __restrict__ x,
                           const int*   __restrict__ ei,
                           const float* __restrict__ s,
                           const float* __restrict__ Wroot1, const float* __restrict__ Wrel1,
                           const float* __restrict__ b1,
                           const float* __restrict__ b2, const float* __restrict__ b3,
                           const unsigned short* __restrict__ wpack,
                           const float* __restrict__ fcw, const float* __restrict__ fcb,
                           float* __restrict__ out, int nE)
{
    __shared__ __align__(16) char smem[SMEM_TOTAL];
    unsigned short* bcat = (unsigned short*)smem;
    unsigned short* hT   = (unsigned short*)(smem + OFF_HT);
    unsigned short* adjb = (unsigned short*)(smem + OFF_ADJ);
    unsigned short* sT   = (unsigned short*)(smem + OFF_ST);
    float*          xl   = (float*)(smem + OFF_XL);

    const int g = blockIdx.x, tid = threadIdx.x, lane = tid & 63, wid = tid >> 6;
    const int gnode = g * NPER, gedge = g * EPER;
    const int* srcp = ei;
    const int* dstp = ei + nE;
    unsigned int* adj32 = (unsigned int*)adjb;
    unsigned int* sT32  = (unsigned int*)sT;
    unsigned int* h32   = (unsigned int*)bcat;
    unsigned int* ht32  = (unsigned int*)hT;

    // ---- zero init ----
    // NaN-safety rule: any uninit LDS multiplied by zero must be zeroed instead
    // (0*Inf=NaN, and relu maps NaN->0 which collapses the whole net to 0).
    // Uninit is allowed ONLY where the MFMA D-rows are discarded unread.
    for (int i = tid; i < NPER * (AJW / 2); i += 256) adj32[i] = 0u;   // adjb rows<68
    for (int i = tid; i < 8 * (AJW / 2); i += 256) sT32[i] = 0u;       // sT rows 0..7
    for (int i = tid; i < NPER * 32; i += 256)                          // bcat agg k=0..63, rows<68
        h32[(i >> 5) * 128 + (i & 31)] = 0u;
    for (int i = tid; i < 128 * 10; i += 256)                           // hT cols 68..87, all 128 rows
        ht32[(i / 10) * (HTW / 2) + 34 + (i % 10)] = 0u;
    for (int i = tid; i < NPER * 2; i += 256) xl[i] = x[gnode * 2 + i];
    __syncthreads();

    // ---- edges -> adjacency counts (u16 halves of u32, atomic) ----
    for (int e = tid; e < EPER; e += 256) {
        int s_ = srcp[gedge + e] - gnode;
        int d_ = dstp[gedge + e] - gnode;
        int idx = d_ * AJW + s_;
        atomicAdd(&adj32[idx >> 1], (idx & 1) ? 0x10000u : 1u);
    }
    __syncthreads();
    // in-place convert u16 counts -> bf16
    for (int i = tid; i < NPER * (AJW / 2); i += 256) {
        unsigned int u = adj32[i];
        if (u) {
            adj32[i] = (unsigned int)f2bf((float)(u & 0xffffu))
                     | ((unsigned int)f2bf((float)(u >> 16)) << 16);
        }
    }
    __syncthreads();

    // ---- layer-1 A prep (aggx via Adj row-dot) + softmax(s)^T ----
    if (tid < 136) {
        int i = tid >> 1, ft = tid & 1;
        float a = 0.f;
        for (int j = 0; j < NPER; ++j) a += bf2f(adjb[i * AJW + j]) * xl[j * 2 + ft];
        *(unsigned short*)((char*)bcat + swzB(i, ft * 2))     = f2bf(a);
        *(unsigned short*)((char*)bcat + swzB(i, 4 + ft * 2)) = f2bf(xl[i * 2 + ft]);
    } else if (tid < 204) {
        int i = tid - 136;
        float v[NC]; float m = -1e30f;
        #pragma unroll
        for (int c = 0; c < NC; ++c) { v[c] = s[(gnode + i) * NC + c]; m = fmaxf(m, v[c]); }
        float sum = 0.f;
        #pragma unroll
        for (int c = 0; c < NC; ++c) { v[c] = __expf(v[c] - m); sum += v[c]; }
        float inv = 1.f / sum;
        #pragma unroll
        for (int c = 0; c < NC; ++c) sT[c * AJW + i] = f2bf(v[c] * inv);
    }
    __syncthreads();

    const int arow = lane & 15, aq = lane >> 4, akB = aq * 16, akE = aq * 8;

    // epilogue: acc + bias -> relu -> bcat h-half (scalar) AND hT (b64 per 4 rows)
    auto epilogue_h = [&](f32x4 (&acc)[5][2], const float* __restrict__ bv) {
        #pragma unroll
        for (int c2 = 0; c2 < 2; ++c2) {
            int f = (wid * 2 + c2) * 16 + arow;
            float bias = bv[f];
            #pragma unroll
            for (int m = 0; m < 5; ++m) {
                int rbase = m * 16 + aq * 4;
                if (rbase < NPER) {                 // rbase multiple of 4; rbase+3 <= 67
                    ushort4v w;
                    #pragma unroll
                    for (int i2 = 0; i2 < 4; ++i2) {
                        float v = acc[m][c2][i2] + bias;
                        v = v > 0.f ? v : 0.f;
                        unsigned short us = f2bf_c(v);
                        w[i2] = us;
                        *(unsigned short*)((char*)bcat + swzB(rbase + i2, (FH + f) * 2)) = us;
                    }
                    *(ushort4v*)(hT + f * HTW + rbase) = w;
                }
            }
        }
    };

    // ---- layer 1: h = relu([aggx|x] @ Wcat1 + b1), K=32 MFMA ----
    // B-fragment zero for k>=4; bcat agg k=0..63 zeroed above -> no NaN hazard.
    {
        f32x4 acc[5][2];
        #pragma unroll
        for (int m = 0; m < 5; ++m) { acc[m][0] = (f32x4)0.f; acc[m][1] = (f32x4)0.f; }
        short8 bf[2];
        #pragma unroll
        for (int c2 = 0; c2 < 2; ++c2) {
            int f = (wid * 2 + c2) * 16 + arow;
            #pragma unroll
            for (int j = 0; j < 8; ++j) {
                float wv = 0.f;
                if (aq == 0) {              // k = j, only k<4 nonzero
                    if (j < 2) wv = Wrel1[j * FH + f];
                    else if (j < 4) wv = Wroot1[(j - 2) * FH + f];
                }
                bf[c2][j] = (short)f2bf(wv);
            }
        }
        #pragma unroll
        for (int m = 0; m < 5; ++m) {
            short8 a = *(const short8*)((char*)bcat + swzB(m * 16 + arow, akB));
            acc[m][0] = __builtin_amdgcn_mfma_f32_16x16x32_bf16(a, bf[0], acc[m][0], 0, 0, 0);
            acc[m][1] = __builtin_amdgcn_mfma_f32_16x16x32_bf16(a, bf[1], acc[m][1], 0, 0, 0);
        }
        epilogue_h(acc, b1);
    }
    __syncthreads();

    // ---- layers 2,3: agg = Adj@h (B from hT), then h' = relu([agg|h]@Wcat+b) ----
    #pragma unroll 1
    for (int L = 0; L < 2; ++L) {
        // agg GEMM: A=adjb rows (rows>=68 spill-read -> D rows discarded),
        //           B = h[src][f] = hT[f][src..src+8] (cols 68..87 zeroed)
        f32x4 acc[5][2];
        #pragma unroll
        for (int m = 0; m < 5; ++m) { acc[m][0] = (f32x4)0.f; acc[m][1] = (f32x4)0.f; }
        #pragma unroll
        for (int kt = 0; kt < 3; ++kt) {
            int cb = kt * 32 + akE; if (cb >= HTW) cb = 0;   // keep read in hT bounds
            short8 bg[2];
            #pragma unroll
            for (int c2 = 0; c2 < 2; ++c2) {
                int f = (wid * 2 + c2) * 16 + arow;
                bg[c2] = *(const short8*)(hT + f * HTW + cb);
            }
            #pragma unroll
            for (int m = 0; m < 5; ++m) {
                short8 a = *(const short8*)(adjb + (m * 16 + arow) * AJW + kt * 32 + akE);
                acc[m][0] = __builtin_amdgcn_mfma_f32_16x16x32_bf16(a, bg[0], acc[m][0], 0, 0, 0);
                acc[m][1] = __builtin_amdgcn_mfma_f32_16x16x32_bf16(a, bg[1], acc[m][1], 0, 0, 0);
            }
        }
        // agg epilogue -> bcat agg-half (no bias/relu), rows < 68
        #pragma unroll
        for (int c2 = 0; c2 < 2; ++c2) {
            int f = (wid * 2 + c2) * 16 + arow;
            #pragma unroll
            for (int m = 0; m < 5; ++m) {
                int rbase = m * 16 + aq * 4;
                if (rbase < NPER) {
                    #pragma unroll
                    for (int i2 = 0; i2 < 4; ++i2)
                        *(unsigned short*)((char*)bcat + swzB(rbase + i2, f * 2)) = f2bf_c(acc[m][c2][i2]);
                }
            }
        }
        __syncthreads();

        // main GEMM: [agg|h] @ Wcat, K=256; A=bcat rows, B=wpack (global, L2)
        f32x4 acc2[5][2];
        #pragma unroll
        for (int m = 0; m < 5; ++m) { acc2[m][0] = (f32x4)0.f; acc2[m][1] = (f32x4)0.f; }
        const unsigned short* wsL = wpack + (L << 15);
        for (int t = 0; t < 8; ++t) {
            short8 bf0 = *(const short8*)(wsL + (((t * 8 + wid * 2 + 0) * 64 + lane) << 3));
            short8 bf1 = *(const short8*)(wsL + (((t * 8 + wid * 2 + 1) * 64 + lane) << 3));
            #pragma unroll
            for (int m = 0; m < 5; ++m) {
                short8 a = *(const short8*)((char*)bcat + swzB(m * 16 + arow, t * 64 + akB));
                acc2[m][0] = __builtin_amdgcn_mfma_f32_16x16x32_bf16(a, bf0, acc2[m][0], 0, 0, 0);
                acc2[m][1] = __builtin_amdgcn_mfma_f32_16x16x32_bf16(a, bf1, acc2[m][1], 0, 0, 0);
            }
        }
        __syncthreads();                 // all A reads done before h/hT overwrite
        epilogue_h(acc2, L ? b3 : b2);
        __syncthreads();
    }

    // ---- diff-pool: xp = sT @ h (B from hT); A rows 8..15 uninit -> D rows discarded ----
    float* xpf = (float*)(smem + OFF_ADJ);   // overlay: adjb dead after L3 agg GEMM
    {
        f32x4 accp[2]; accp[0] = (f32x4)0.f; accp[1] = (f32x4)0.f;
        #pragma unroll
        for (int kt = 0; kt < 3; ++kt) {
            int cb = kt * 32 + akE; if (cb >= HTW) cb = 0;
            short8 bg[2];
            #pragma unroll
            for (int c2 = 0; c2 < 2; ++c2) {
                int f = (wid * 2 + c2) * 16 + arow;
                bg[c2] = *(const short8*)(hT + f * HTW + cb);
            }
            short8 a = *(const short8*)(sT + arow * AJW + kt * 32 + akE);
            accp[0] = __builtin_amdgcn_mfma_f32_16x16x32_bf16(a, bg[0], accp[0], 0, 0, 0);
            accp[1] = __builtin_amdgcn_mfma_f32_16x16x32_bf16(a, bg[1], accp[1], 0, 0, 0);
        }
        #pragma unroll
        for (int c2 = 0; c2 < 2; ++c2) {
            int f = (wid * 2 + c2) * 16 + arow;
            if (aq < 2) {
                #pragma unroll
                for (int i2 = 0; i2 < 4; ++i2) xpf[(aq * 4 + i2) * FH + f] = accp[c2][i2];
            }
        }
    }
    __syncthreads();

    // ---- maxpool (1,8) + FC ----
    float* red = xpf + NC * FH;
    float partial = 0.f;
    if (tid < 128) {
        int c = tid >> 4, q = tid & 15;
        float m = xpf[c * FH + q * 8];
        #pragma unroll
        for (int j = 1; j < 8; ++j) m = fmaxf(m, xpf[c * FH + q * 8 + j]);
        partial = m * fcw[tid];
    }
    if (tid < 128) red[tid] = partial;
    __syncthreads();
    if (tid < 64) {
        float v = red[tid] + red[tid + 64];
        #pragma unroll
        for (int off = 32; off > 0; off >>= 1) v += __shfl_down(v, off, 64);
        if (tid == 0) out[g] = v + fcb[0];
    }
}

extern "C" void kernel_launch(void* const* d_in, const int* in_sizes, int n_in,
                              void* d_out, int out_size, void* d_ws, size_t ws_size,
                              hipStream_t stream) {
    const float* x      = (const float*)d_in[0];
    const int*   ei     = (const int*)d_in[1];
    // d_in[2] = adj: dead code in the reference
    const float* s      = (const float*)d_in[3];
    const float* Wroot1 = (const float*)d_in[4];
    const float* Wrel1  = (const float*)d_in[5];
    const float* b1     = (const float*)d_in[6];
    const float* Wroot2 = (const float*)d_in[7];
    const float* Wrel2  = (const float*)d_in[8];
    const float* b2     = (const float*)d_in[9];
    const float* Wroot3 = (const float*)d_in[10];
    const float* Wrel3  = (const float*)d_in[11];
    const float* b3     = (const float*)d_in[12];
    const float* fcw    = (const float*)d_in[13];
    const float* fcb    = (const float*)d_in[14];
    float* out = (float*)d_out;
    unsigned short* wpack = (unsigned short*)d_ws;   // 65536 bf16 = 128 KB

    const int nE = in_sizes[1] / 2;
    const int B  = in_sizes[3] / (NPER * NC);

    pack_w<<<256, 256, 0, stream>>>(Wrel2, Wroot2, Wrel3, Wroot3, wpack);
    gnn_kernel<<<B, 256, 0, stream>>>(x, ei, s,
                                      Wroot1, Wrel1, b1,
                                      b2, b3, wpack,
                                      fcw, fcb, out, nE);
}